// Round 2
// baseline (2549.295 us; speedup 1.0000x reference)
//
#include <hip/hip_runtime.h>
#include <hip/hip_bf16.h>

#define HW 4096
#define C_ 256
#define B_ 4

static const size_t CHW = (size_t)C_ * HW;  // 1,048,576 elements per batch per tensor

// ---------- helpers ----------
__device__ __forceinline__ unsigned long long pack_key(float v, int i) {
    // orderable float bits; tie-break: smaller l wins under max (store ~l)
    unsigned u = __float_as_uint(v);
    u = (u & 0x80000000u) ? ~u : (u | 0x80000000u);
    return ((unsigned long long)u << 32) | (unsigned long long)(0xFFFFFFFFu - (unsigned)i);
}

// ---------- K1a: per-pixel squared sum over channels of blur ----------
__global__ __launch_bounds__(256) void sqsum_kernel(const float* __restrict__ frb,
                                                    float* __restrict__ sbuf) {
    int b = blockIdx.x;
    int ij = blockIdx.y * 256 + threadIdx.x;
    const float* p = frb + (size_t)b * CHW + ij;
    float s = 0.f;
#pragma unroll 8
    for (int c = 0; c < C_; ++c) {
        float v = p[(size_t)c * HW];
        s = fmaf(v, v, s);
    }
    sbuf[b * HW + ij] = s;
}

// ---------- K1b: 3x3 box sum -> 1/max(sqrt, eps) ----------
__global__ __launch_bounds__(256) void invn_kernel(const float* __restrict__ sbuf,
                                                   float* __restrict__ invn) {
    int b = blockIdx.x;
    int l = blockIdx.y * 256 + threadIdx.x;
    int lh = l >> 6, lw = l & 63;
    float s = 0.f;
#pragma unroll
    for (int dh = -1; dh <= 1; ++dh) {
        int h = lh + dh;
        if ((unsigned)h >= 64u) continue;
#pragma unroll
        for (int dw = -1; dw <= 1; ++dw) {
            int w = lw + dw;
            if ((unsigned)w >= 64u) continue;
            s += sbuf[b * HW + h * 64 + w];
        }
    }
    float n = sqrtf(s);
    invn[b * HW + l] = 1.0f / fmaxf(n, 1e-12f);
}

// ---------- K2: fp32 Gram GEMM  G[m][col] = sum_c fc[c][m] * frb[c][l_start+col] ----------
#define TBK 32
__global__ __launch_bounds__(256) void gram_kernel(const float* __restrict__ Amat,  // fc[b]: [256][4096]
                                                   const float* __restrict__ Bmat,  // frb[b]: [256][4096]
                                                   float* __restrict__ G,
                                                   int l_start, int CWP) {
    __shared__ float As[TBK][128];
    __shared__ float Bs[TBK][128];
    int m0 = blockIdx.y * 128;
    int l0g = l_start + blockIdx.x * 128;  // global column base (may be halo / out of range)
    bool inrange = (l0g >= 0 && l0g < HW);
    int tid = threadIdx.x;
    int tx = tid & 15;       // l-direction
    int ty = tid >> 4;       // m-direction
    float acc[8][8] = {};

    if (inrange) {
        for (int k0 = 0; k0 < C_; k0 += TBK) {
#pragma unroll
            for (int it = 0; it < 4; ++it) {
                int idx = tid + it * 256;     // 0..1023
                int r = idx >> 5;             // row in K (0..31)
                int c4 = idx & 31;            // float4 column
                float4 av = *reinterpret_cast<const float4*>(Amat + (size_t)(k0 + r) * HW + m0 + c4 * 4);
                *reinterpret_cast<float4*>(&As[r][c4 * 4]) = av;
                float4 bv = *reinterpret_cast<const float4*>(Bmat + (size_t)(k0 + r) * HW + l0g + c4 * 4);
                *reinterpret_cast<float4*>(&Bs[r][c4 * 4]) = bv;
            }
            __syncthreads();
#pragma unroll
            for (int k = 0; k < TBK; ++k) {
                float a[8], bb[8];
                *(float4*)&a[0] = *(float4*)&As[k][ty * 8];
                *(float4*)&a[4] = *(float4*)&As[k][ty * 8 + 4];
                *(float4*)&bb[0] = *(float4*)&Bs[k][tx * 8];
                *(float4*)&bb[4] = *(float4*)&Bs[k][tx * 8 + 4];
#pragma unroll
                for (int i = 0; i < 8; ++i)
#pragma unroll
                    for (int j = 0; j < 8; ++j)
                        acc[i][j] = fmaf(a[i], bb[j], acc[i][j]);
            }
            __syncthreads();
        }
    }
#pragma unroll
    for (int i = 0; i < 8; ++i) {
        int m = m0 + ty * 8 + i;
        float* row = G + (size_t)m * CWP + blockIdx.x * 128 + tx * 8;
        *(float4*)row = *(float4*)&acc[i][0];
        *(float4*)(row + 4) = *(float4*)&acc[i][4];
    }
}

// ---------- K3: 9-diagonal-shift sum + argmax over l (packed atomicMax) ----------
// grid: (mh=64, nY), block 256 (4 waves). Wave owns 16 mw values; lanes = lw.
__global__ __launch_bounds__(256) void argmax_kernel(const float* __restrict__ G,
                                                     const float* __restrict__ invn,
                                                     unsigned long long* __restrict__ keys,
                                                     int lh_chunk0, int RPB,
                                                     int l_start, int CWP) {
    int mh = blockIdx.x;
    int lh_base = lh_chunk0 + blockIdx.y * RPB;
    int wave = threadIdx.x >> 6;
    int lane = threadIdx.x & 63;

    float maxv[16];
    int maxi[16];
#pragma unroll
    for (int i = 0; i < 16; ++i) { maxv[i] = -INFINITY; maxi[i] = 0; }

    for (int lhs = 0; lhs < RPB; ++lhs) {
        int lh = lh_base + lhs;
        int l = lh * 64 + lane;
        float inv = invn[l];
#pragma unroll
        for (int mi = 0; mi < 16; ++mi) {
            int mw = wave * 16 + mi;
            float R = 0.f;
#pragma unroll
            for (int dh = -1; dh <= 1; ++dh) {
                int mh2 = mh + dh, lh2 = lh + dh;
                if ((unsigned)mh2 >= 64u || (unsigned)lh2 >= 64u) continue;
#pragma unroll
                for (int dw = -1; dw <= 1; ++dw) {
                    int mw2 = mw + dw;
                    if ((unsigned)mw2 >= 64u) continue;
                    int lw2 = lane + dw;
                    const float* row = G + (size_t)(mh2 * 64 + mw2) * CWP + (lh2 * 64 - l_start);
                    float v = ((unsigned)lw2 < 64u) ? row[lw2] : 0.f;
                    R += v;
                }
            }
            float score = R * inv;
            if (score > maxv[mi]) { maxv[mi] = score; maxi[mi] = l; }  // ascending l: first max kept
        }
    }
#pragma unroll
    for (int mi = 0; mi < 16; ++mi) {
        float v = maxv[mi];
        int idx = maxi[mi];
#pragma unroll
        for (int off = 32; off >= 1; off >>= 1) {
            float v2 = __shfl_xor(v, off);
            int i2 = __shfl_xor(idx, off);
            if (v2 > v || (v2 == v && i2 < idx)) { v = v2; idx = i2; }
        }
        if (lane == 0) {
            int m = mh * 64 + wave * 16 + mi;
            atomicMax(&keys[m], pack_key(v, idx));
        }
    }
}

// ---------- K4: gather matched refer patches, fold, add current, fp32 out ----------
__global__ __launch_bounds__(256) void fold_kernel(const float* __restrict__ fc,
                                                   const float* __restrict__ fr,
                                                   const unsigned long long* __restrict__ keys,
                                                   float* __restrict__ out) {
    int i = blockIdx.x;  // output row (h)
    int b = blockIdx.y;
    __shared__ int pos[64][9];
    for (int p = threadIdx.x; p < 576; p += 256) {
        int j = p / 9, k = p % 9;
        int kh = k / 3, kw = k % 3;
        int mhp = i + 1 - kh, mwp = j + 1 - kw;
        int ps = -1;
        if ((unsigned)mhp < 64u && (unsigned)mwp < 64u) {
            unsigned long long kk = keys[(size_t)b * HW + mhp * 64 + mwp];
            int idx = (int)(0xFFFFFFFFu - (unsigned)(kk & 0xFFFFFFFFull));
            int sh = (idx >> 6) + kh - 1;
            int sw = (idx & 63) + kw - 1;
            if ((unsigned)sh < 64u && (unsigned)sw < 64u) ps = sh * 64 + sw;
        }
        pos[j][k] = ps;
    }
    __syncthreads();
    int j = threadIdx.x & 63, cq = threadIdx.x >> 6;
    int pr[9];
#pragma unroll
    for (int k = 0; k < 9; ++k) pr[k] = pos[j][k];
    for (int c = cq; c < C_; c += 4) {
        const float* frow = fr + (size_t)b * CHW + (size_t)c * HW;
        float acc = fc[(size_t)b * CHW + (size_t)c * HW + i * 64 + j];
#pragma unroll
        for (int k = 0; k < 9; ++k) {
            int p = pr[k];
            float v = frow[p < 0 ? 0 : p];
            acc += (p >= 0) ? v : 0.f;
        }
        out[(size_t)b * CHW + (size_t)c * HW + i * 64 + j] = acc;
    }
}

// ---------- launch ----------
extern "C" void kernel_launch(void* const* d_in, const int* in_sizes, int n_in,
                              void* d_out, int out_size, void* d_ws, size_t ws_size,
                              hipStream_t stream) {
    const float* fc = (const float*)d_in[0];   // feature_current
    const float* fr = (const float*)d_in[1];   // feature_refer
    const float* frb = (const float*)d_in[2];  // feature_refer_blur
    float* out = (float*)d_out;

    char* ws = (char*)d_ws;
    unsigned long long* keys = (unsigned long long*)ws;  // 4*4096*8   = 131072 B
    float* invn = (float*)(ws + 131072);                 // 4*4096*4   =  65536 B
    float* sbuf = (float*)(ws + 196608);                 // 4*4096*4   =  65536 B
    float* G = (float*)(ws + 262144);

    // Pick largest l-chunk width that fits: full 4096 (no halo) or halo'd chunks (+-128 cols).
    int CW = 4096, PAD = 0;
    while (CW >= 256) {
        PAD = (CW == 4096) ? 0 : 128;
        size_t need = 262144 + (size_t)HW * (CW + 2 * PAD) * 4;
        if (need <= ws_size) break;
        CW >>= 1;
    }
    int CWP = CW + 2 * PAD;

    hipMemsetAsync(keys, 0, 131072, stream);
    sqsum_kernel<<<dim3(B_, 16), 256, 0, stream>>>(frb, sbuf);
    invn_kernel<<<dim3(B_, 16), 256, 0, stream>>>(sbuf, invn);

    for (int b = 0; b < B_; ++b) {
        for (int cb = 0; cb < HW; cb += CW) {
            int l_start = cb - PAD;
            gram_kernel<<<dim3(CWP / 128, 32), 256, 0, stream>>>(
                fc + (size_t)b * CHW, frb + (size_t)b * CHW, G, l_start, CWP);
            int ROWS = CW / 64;
            int RPB = ROWS < 16 ? ROWS : 16;
            int nY = ROWS / RPB;
            argmax_kernel<<<dim3(64, nY), 256, 0, stream>>>(
                G, invn + (size_t)b * HW, keys + (size_t)b * HW,
                cb / 64, RPB, l_start, CWP);
        }
    }
    fold_kernel<<<dim3(64, B_), 256, 0, stream>>>(fc, fr, keys, out);
}

// Round 3
// 721.081 us; speedup vs baseline: 3.5354x; 3.5354x over previous
//
#include <hip/hip_runtime.h>
#include <hip/hip_bf16.h>

#define HW 4096
#define C_ 256
#define B_ 4

static const size_t CHW = (size_t)C_ * HW;  // 1,048,576 elements per batch per tensor

// ---------- helpers ----------
__device__ __forceinline__ unsigned long long pack_key(float v, int i) {
    // orderable float bits; tie-break: smaller l wins under max (store ~l)
    unsigned u = __float_as_uint(v);
    u = (u & 0x80000000u) ? ~u : (u | 0x80000000u);
    return ((unsigned long long)u << 32) | (unsigned long long)(0xFFFFFFFFu - (unsigned)i);
}

// ---------- K1a: per-pixel squared sum over channels of blur ----------
__global__ __launch_bounds__(256) void sqsum_kernel(const float* __restrict__ frb,
                                                    float* __restrict__ sbuf) {
    int b = blockIdx.x;
    int ij = blockIdx.y * 256 + threadIdx.x;
    const float* p = frb + (size_t)b * CHW + ij;
    float s = 0.f;
#pragma unroll 8
    for (int c = 0; c < C_; ++c) {
        float v = p[(size_t)c * HW];
        s = fmaf(v, v, s);
    }
    sbuf[b * HW + ij] = s;
}

// ---------- K1b: 3x3 box sum -> 1/max(sqrt, eps) ----------
__global__ __launch_bounds__(256) void invn_kernel(const float* __restrict__ sbuf,
                                                   float* __restrict__ invn) {
    int b = blockIdx.x;
    int l = blockIdx.y * 256 + threadIdx.x;
    int lh = l >> 6, lw = l & 63;
    float s = 0.f;
#pragma unroll
    for (int dh = -1; dh <= 1; ++dh) {
        int h = lh + dh;
        if ((unsigned)h >= 64u) continue;
#pragma unroll
        for (int dw = -1; dw <= 1; ++dw) {
            int w = lw + dw;
            if ((unsigned)w >= 64u) continue;
            s += sbuf[b * HW + h * 64 + w];
        }
    }
    float n = sqrtf(s);
    invn[b * HW + l] = 1.0f / fmaxf(n, 1e-12f);
}

// ---------- K2: fp32 Gram GEMM  G[m][col] = sum_c fc[c][m] * frb[c][l_start+col] ----------
#define TBK 32
__global__ __launch_bounds__(256) void gram_kernel(const float* __restrict__ Amat,  // fc[b]: [256][4096]
                                                   const float* __restrict__ Bmat,  // frb[b]: [256][4096]
                                                   float* __restrict__ G,
                                                   int l_start, int CWP) {
    __shared__ float As[TBK][128];
    __shared__ float Bs[TBK][128];
    int m0 = blockIdx.y * 128;
    int l0g = l_start + blockIdx.x * 128;  // global column base (may be halo / out of range)
    bool inrange = (l0g >= 0 && l0g < HW);
    int tid = threadIdx.x;
    int tx = tid & 15;       // l-direction
    int ty = tid >> 4;       // m-direction
    float acc[8][8] = {};

    if (inrange) {
        for (int k0 = 0; k0 < C_; k0 += TBK) {
#pragma unroll
            for (int it = 0; it < 4; ++it) {
                int idx = tid + it * 256;     // 0..1023
                int r = idx >> 5;             // row in K (0..31)
                int c4 = idx & 31;            // float4 column
                float4 av = *reinterpret_cast<const float4*>(Amat + (size_t)(k0 + r) * HW + m0 + c4 * 4);
                *reinterpret_cast<float4*>(&As[r][c4 * 4]) = av;
                float4 bv = *reinterpret_cast<const float4*>(Bmat + (size_t)(k0 + r) * HW + l0g + c4 * 4);
                *reinterpret_cast<float4*>(&Bs[r][c4 * 4]) = bv;
            }
            __syncthreads();
#pragma unroll
            for (int k = 0; k < TBK; ++k) {
                float a[8], bb[8];
                *(float4*)&a[0] = *(float4*)&As[k][ty * 8];
                *(float4*)&a[4] = *(float4*)&As[k][ty * 8 + 4];
                *(float4*)&bb[0] = *(float4*)&Bs[k][tx * 8];
                *(float4*)&bb[4] = *(float4*)&Bs[k][tx * 8 + 4];
#pragma unroll
                for (int i = 0; i < 8; ++i)
#pragma unroll
                    for (int j = 0; j < 8; ++j)
                        acc[i][j] = fmaf(a[i], bb[j], acc[i][j]);
            }
            __syncthreads();
        }
    }
#pragma unroll
    for (int i = 0; i < 8; ++i) {
        int m = m0 + ty * 8 + i;
        float* row = G + (size_t)m * CWP + blockIdx.x * 128 + tx * 8;
        *(float4*)row = *(float4*)&acc[i][0];
        *(float4*)(row + 4) = *(float4*)&acc[i][4];
    }
}

// ---------- K3: 9-diagonal-shift sum + argmax over l ----------
// grid: (mh=64, nY), block 256 = 4 waves. Wave handles mw in [wave*16, wave*16+16);
// lanes = lw. Each block covers 4 lh rows; dw taps via lane shuffles, rows coalesced.
__global__ __launch_bounds__(256) void argmax_kernel(const float* __restrict__ G,
                                                     const float* __restrict__ invn,
                                                     unsigned long long* __restrict__ keys,
                                                     int lh0, int l_start, int CWP) {
    int mh = blockIdx.x;
    int lh_base = lh0 + blockIdx.y * 4;
    int wave = threadIdx.x >> 6;
    int lane = threadIdx.x & 63;
    int mwbase = wave * 16;

    float maxv[16];
    int maxi[16];
#pragma unroll
    for (int i = 0; i < 16; ++i) { maxv[i] = -INFINITY; maxi[i] = 0; }

    for (int lhs = 0; lhs < 4; ++lhs) {
        int lh = lh_base + lhs;
        int l = lh * 64 + lane;
        float inv = invn[l];
        float R[16];
#pragma unroll
        for (int i = 0; i < 16; ++i) R[i] = 0.f;

#pragma unroll
        for (int dh = -1; dh <= 1; ++dh) {
            if ((unsigned)(mh + dh) >= 64u || (unsigned)(lh + dh) >= 64u) continue;
            const float* Gb = G + (size_t)((mh + dh) * 64) * CWP + ((lh + dh) * 64 - l_start) + lane;
            float v[18];
#pragma unroll
            for (int j = 0; j < 18; ++j) {
                int mw2 = mwbase - 1 + j;
                int mwc = min(max(mw2, 0), 63);
                float t = Gb[(size_t)mwc * CWP];
                v[j] = ((unsigned)mw2 < 64u) ? t : 0.f;  // rows outside [0,64) contribute 0
            }
#pragma unroll
            for (int mi = 0; mi < 16; ++mi) {
                float a = __shfl_up(v[mi], 1);       // tap (dw=-1): row mw-1, lane-1
                float c = __shfl_down(v[mi + 2], 1); // tap (dw=+1): row mw+1, lane+1
                float s = v[mi + 1];                 // tap (dw=0)
                s += (lane > 0) ? a : 0.f;
                s += (lane < 63) ? c : 0.f;
                R[mi] += s;
            }
        }
#pragma unroll
        for (int mi = 0; mi < 16; ++mi) {
            float score = R[mi] * inv;
            if (score > maxv[mi]) { maxv[mi] = score; maxi[mi] = l; }  // ascending l keeps first max
        }
    }

#pragma unroll
    for (int mi = 0; mi < 16; ++mi) {
        float v = maxv[mi];
        int idx = maxi[mi];
#pragma unroll
        for (int off = 32; off >= 1; off >>= 1) {
            float v2 = __shfl_xor(v, off);
            int i2 = __shfl_xor(idx, off);
            if (v2 > v || (v2 == v && i2 < idx)) { v = v2; idx = i2; }
        }
        if (lane == 0) {
            int m = mh * 64 + mwbase + mi;
            atomicMax(&keys[m], pack_key(v, idx));
        }
    }
}

// ---------- K4: gather matched refer patches, fold, add current, fp32 out ----------
__global__ __launch_bounds__(256) void fold_kernel(const float* __restrict__ fc,
                                                   const float* __restrict__ fr,
                                                   const unsigned long long* __restrict__ keys,
                                                   float* __restrict__ out) {
    int i = blockIdx.x;  // output row (h)
    int b = blockIdx.y;
    __shared__ int pos[64][9];
    for (int p = threadIdx.x; p < 576; p += 256) {
        int j = p / 9, k = p % 9;
        int kh = k / 3, kw = k % 3;
        int mhp = i + 1 - kh, mwp = j + 1 - kw;
        int ps = -1;
        if ((unsigned)mhp < 64u && (unsigned)mwp < 64u) {
            unsigned long long kk = keys[(size_t)b * HW + mhp * 64 + mwp];
            int idx = (int)(0xFFFFFFFFu - (unsigned)(kk & 0xFFFFFFFFull));
            int sh = (idx >> 6) + kh - 1;
            int sw = (idx & 63) + kw - 1;
            if ((unsigned)sh < 64u && (unsigned)sw < 64u) ps = sh * 64 + sw;
        }
        pos[j][k] = ps;
    }
    __syncthreads();
    int j = threadIdx.x & 63, cq = threadIdx.x >> 6;
    int pr[9];
#pragma unroll
    for (int k = 0; k < 9; ++k) pr[k] = pos[j][k];
    for (int c = cq; c < C_; c += 4) {
        const float* frow = fr + (size_t)b * CHW + (size_t)c * HW;
        float acc = fc[(size_t)b * CHW + (size_t)c * HW + i * 64 + j];
#pragma unroll
        for (int k = 0; k < 9; ++k) {
            int p = pr[k];
            float v = frow[p < 0 ? 0 : p];
            acc += (p >= 0) ? v : 0.f;
        }
        out[(size_t)b * CHW + (size_t)c * HW + i * 64 + j] = acc;
    }
}

// ---------- launch ----------
extern "C" void kernel_launch(void* const* d_in, const int* in_sizes, int n_in,
                              void* d_out, int out_size, void* d_ws, size_t ws_size,
                              hipStream_t stream) {
    const float* fc = (const float*)d_in[0];   // feature_current
    const float* fr = (const float*)d_in[1];   // feature_refer
    const float* frb = (const float*)d_in[2];  // feature_refer_blur
    float* out = (float*)d_out;

    char* ws = (char*)d_ws;
    unsigned long long* keys = (unsigned long long*)ws;  // 4*4096*8   = 131072 B
    float* invn = (float*)(ws + 131072);                 // 4*4096*4   =  65536 B
    float* sbuf = (float*)(ws + 196608);                 // 4*4096*4   =  65536 B
    float* G = (float*)(ws + 262144);

    // Pick largest l-chunk width that fits: full 4096 (no halo) or halo'd chunks (+-128 cols).
    int CW = 4096, PAD = 0;
    while (CW >= 256) {
        PAD = (CW == 4096) ? 0 : 128;
        size_t need = 262144 + (size_t)HW * (CW + 2 * PAD) * 4;
        if (need <= ws_size) break;
        CW >>= 1;
    }
    int CWP = CW + 2 * PAD;

    hipMemsetAsync(keys, 0, 131072, stream);
    sqsum_kernel<<<dim3(B_, 16), 256, 0, stream>>>(frb, sbuf);
    invn_kernel<<<dim3(B_, 16), 256, 0, stream>>>(sbuf, invn);

    for (int b = 0; b < B_; ++b) {
        for (int cb = 0; cb < HW; cb += CW) {
            int l_start = cb - PAD;
            gram_kernel<<<dim3(CWP / 128, 32), 256, 0, stream>>>(
                fc + (size_t)b * CHW, frb + (size_t)b * CHW, G, l_start, CWP);
            int ROWS = CW / 64;
            argmax_kernel<<<dim3(64, ROWS / 4), 256, 0, stream>>>(
                G, invn + (size_t)b * HW, keys + (size_t)b * HW,
                cb / 64, l_start, CWP);
        }
    }
    fold_kernel<<<dim3(64, B_), 256, 0, stream>>>(fc, fr, keys, out);
}

// Round 4
// 527.424 us; speedup vs baseline: 4.8335x; 1.3672x over previous
//
#include <hip/hip_runtime.h>
#include <hip/hip_bf16.h>
#include <stdint.h>

#define HW 4096
#define C_ 256
#define B_ 4

static const size_t CHW = (size_t)C_ * HW;  // 1,048,576 elements per batch per tensor

typedef _Float16 f16;
typedef f16 f16x8 __attribute__((ext_vector_type(8)));
typedef float f32x4 __attribute__((ext_vector_type(4)));

// ---------- helpers ----------
__device__ __forceinline__ unsigned long long pack_key(float v, int i) {
    // orderable float bits; tie-break: smaller l wins under max (store ~l)
    unsigned u = __float_as_uint(v);
    u = (u & 0x80000000u) ? ~u : (u | 0x80000000u);
    return ((unsigned long long)u << 32) | (unsigned long long)(0xFFFFFFFFu - (unsigned)i);
}

// ---------- K1a: per-pixel squared sum over channels of blur ----------
__global__ __launch_bounds__(256) void sqsum_kernel(const float* __restrict__ frb,
                                                    float* __restrict__ sbuf) {
    int b = blockIdx.x;
    int ij = blockIdx.y * 256 + threadIdx.x;
    const float* p = frb + (size_t)b * CHW + ij;
    float s = 0.f;
#pragma unroll 8
    for (int c = 0; c < C_; ++c) {
        float v = p[(size_t)c * HW];
        s = fmaf(v, v, s);
    }
    sbuf[b * HW + ij] = s;
}

// ---------- K1b: 3x3 box sum -> 1/max(sqrt, eps) ----------
__global__ __launch_bounds__(256) void invn_kernel(const float* __restrict__ sbuf,
                                                   float* __restrict__ invn) {
    int b = blockIdx.x;
    int l = blockIdx.y * 256 + threadIdx.x;
    int lh = l >> 6, lw = l & 63;
    float s = 0.f;
#pragma unroll
    for (int dh = -1; dh <= 1; ++dh) {
        int h = lh + dh;
        if ((unsigned)h >= 64u) continue;
#pragma unroll
        for (int dw = -1; dw <= 1; ++dw) {
            int w = lw + dw;
            if ((unsigned)w >= 64u) continue;
            s += sbuf[b * HW + h * 64 + w];
        }
    }
    float n = sqrtf(s);
    invn[b * HW + l] = 1.0f / fmaxf(n, 1e-12f);
}

// ---------- conv: fp32 [256][4096] -> f16 hi/lo, m-major [4096][512] ----------
// z=0: fc -> Af ; z=1: frb -> Bf. Tile 64k x 64m via LDS transpose.
__global__ __launch_bounds__(256) void conv_kernel(const float* __restrict__ fc,
                                                   const float* __restrict__ frb,
                                                   f16* __restrict__ Af,
                                                   f16* __restrict__ Bf) {
    const float* src = blockIdx.z ? frb : fc;
    f16* dst = blockIdx.z ? Bf : Af;
    __shared__ float T[64][65];
    int m0 = blockIdx.x * 64, k0 = blockIdx.y * 64;
    int t = threadIdx.x;
    int kl = t >> 4, mq = (t & 15) * 4;
#pragma unroll
    for (int it = 0; it < 4; ++it) {
        float4 v = *reinterpret_cast<const float4*>(src + (size_t)(k0 + kl + it * 16) * HW + m0 + mq);
        T[kl + it * 16][mq + 0] = v.x;
        T[kl + it * 16][mq + 1] = v.y;
        T[kl + it * 16][mq + 2] = v.z;
        T[kl + it * 16][mq + 3] = v.w;
    }
    __syncthreads();
    int ml = t >> 2, kc = (t & 3) * 16;
    f16x8 h0, h1, lo0, lo1;
#pragma unroll
    for (int j = 0; j < 8; ++j) {
        float a = T[kc + j][ml];
        f16 h = (f16)a;
        h0[j] = h;
        lo0[j] = (f16)(a - (float)h);
        float a2 = T[kc + 8 + j][ml];
        f16 h2 = (f16)a2;
        h1[j] = h2;
        lo1[j] = (f16)(a2 - (float)h2);
    }
    size_t base = (size_t)(m0 + ml) * 512 + k0 + kc;
    *reinterpret_cast<f16x8*>(dst + base) = h0;
    *reinterpret_cast<f16x8*>(dst + base + 8) = h1;
    *reinterpret_cast<f16x8*>(dst + base + 256) = lo0;
    *reinterpret_cast<f16x8*>(dst + base + 264) = lo1;
}

// ---------- K2 (MFMA): G[m][l] = 3-product fp16-split Gram, K=768 ----------
// Af,Bf: [4096][512] f16 (cols 0..255 = hi, 256..511 = lo). 128x128 tile, BK=64.
// LDS XOR-swizzle: slot (row, chunk) holds global chunk (chunk ^ (row&7)); staged via
// inverse-swizzled per-lane global source (gload_lds dest is linear), read swizzled.
__global__ __launch_bounds__(256) void gram_mfma_kernel(const f16* __restrict__ Af,
                                                        const f16* __restrict__ Bf,
                                                        float* __restrict__ G) {
    __shared__ char Asb[16384];  // [128 rows][64 k] f16 = 128 B/row
    __shared__ char Bsb[16384];
    int tid = threadIdx.x;
    int lane = tid & 63;
    int wave = tid >> 6;
    int wr = wave >> 1, wc = wave & 1;
    int m0 = blockIdx.y * 128, l0 = blockIdx.x * 128;
    f32x4 acc[4][4] = {};

    char* lbaseA = Asb + (tid & ~63) * 16;  // wave-uniform; HW adds lane*16
    char* lbaseB = Bsb + (tid & ~63) * 16;

    for (int t = 0; t < 12; ++t) {
        int tt = t & 3;
        int akb = (tt * 64 + ((t >= 4 && t < 8) ? 256 : 0)) * 2;  // bytes into row
        int bkb = (tt * 64 + ((t >= 8) ? 256 : 0)) * 2;
#pragma unroll
        for (int i = 0; i < 4; ++i) {
            int c = i * 256 + tid;
            int m = c >> 3, cl = c & 7;
            int sw = ((cl ^ (m & 7)) << 4);
            const char* ga = (const char*)Af + (size_t)(m0 + m) * 1024 + akb + sw;
            const char* gb = (const char*)Bf + (size_t)(l0 + m) * 1024 + bkb + sw;
            __builtin_amdgcn_global_load_lds(
                (const __attribute__((address_space(1))) uint32_t*)ga,
                (__attribute__((address_space(3))) uint32_t*)(lbaseA + i * 4096), 16, 0, 0);
            __builtin_amdgcn_global_load_lds(
                (const __attribute__((address_space(1))) uint32_t*)gb,
                (__attribute__((address_space(3))) uint32_t*)(lbaseB + i * 4096), 16, 0, 0);
        }
        __syncthreads();  // drains vmcnt before any wave reads LDS
#pragma unroll
        for (int kk = 0; kk < 2; ++kk) {
            f16x8 av[4], bv[4];
#pragma unroll
            for (int q = 0; q < 4; ++q) {
                int mrow = wr * 64 + q * 16 + (lane & 15);
                int nrow = wc * 64 + q * 16 + (lane & 15);
                int ch = ((kk * 4 + (lane >> 4)) ^ (lane & 7)) << 4;
                av[q] = *reinterpret_cast<const f16x8*>(Asb + mrow * 128 + ch);
                bv[q] = *reinterpret_cast<const f16x8*>(Bsb + nrow * 128 + ch);
            }
#pragma unroll
            for (int mi = 0; mi < 4; ++mi)
#pragma unroll
                for (int ni = 0; ni < 4; ++ni)
                    acc[mi][ni] = __builtin_amdgcn_mfma_f32_16x16x32_f16(
                        av[mi], bv[ni], acc[mi][ni], 0, 0, 0);
        }
        __syncthreads();  // all ds_reads done before next stage overwrites
    }
    // epilogue: C/D layout col=lane&15, row=(lane>>4)*4+r
#pragma unroll
    for (int mi = 0; mi < 4; ++mi) {
#pragma unroll
        for (int ni = 0; ni < 4; ++ni) {
            int n = l0 + wc * 64 + ni * 16 + (lane & 15);
            int mr = m0 + wr * 64 + mi * 16 + (lane >> 4) * 4;
#pragma unroll
            for (int r = 0; r < 4; ++r)
                G[(size_t)(mr + r) * HW + n] = acc[mi][ni][r];
        }
    }
}

// ---------- K2 fallback: fp32 Gram GEMM (chunked) ----------
#define TBK 32
__global__ __launch_bounds__(256) void gram_kernel(const float* __restrict__ Amat,
                                                   const float* __restrict__ Bmat,
                                                   float* __restrict__ G,
                                                   int l_start, int CWP) {
    __shared__ float As[TBK][128];
    __shared__ float Bs[TBK][128];
    int m0 = blockIdx.y * 128;
    int l0g = l_start + blockIdx.x * 128;
    bool inrange = (l0g >= 0 && l0g < HW);
    int tid = threadIdx.x;
    int tx = tid & 15;
    int ty = tid >> 4;
    float acc[8][8] = {};

    if (inrange) {
        for (int k0 = 0; k0 < C_; k0 += TBK) {
#pragma unroll
            for (int it = 0; it < 4; ++it) {
                int idx = tid + it * 256;
                int r = idx >> 5;
                int c4 = idx & 31;
                float4 av = *reinterpret_cast<const float4*>(Amat + (size_t)(k0 + r) * HW + m0 + c4 * 4);
                *reinterpret_cast<float4*>(&As[r][c4 * 4]) = av;
                float4 bv = *reinterpret_cast<const float4*>(Bmat + (size_t)(k0 + r) * HW + l0g + c4 * 4);
                *reinterpret_cast<float4*>(&Bs[r][c4 * 4]) = bv;
            }
            __syncthreads();
#pragma unroll
            for (int k = 0; k < TBK; ++k) {
                float a[8], bb[8];
                *(float4*)&a[0] = *(float4*)&As[k][ty * 8];
                *(float4*)&a[4] = *(float4*)&As[k][ty * 8 + 4];
                *(float4*)&bb[0] = *(float4*)&Bs[k][tx * 8];
                *(float4*)&bb[4] = *(float4*)&Bs[k][tx * 8 + 4];
#pragma unroll
                for (int i = 0; i < 8; ++i)
#pragma unroll
                    for (int j = 0; j < 8; ++j)
                        acc[i][j] = fmaf(a[i], bb[j], acc[i][j]);
            }
            __syncthreads();
        }
    }
#pragma unroll
    for (int i = 0; i < 8; ++i) {
        int m = m0 + ty * 8 + i;
        float* row = G + (size_t)m * CWP + blockIdx.x * 128 + tx * 8;
        *(float4*)row = *(float4*)&acc[i][0];
        *(float4*)(row + 4) = *(float4*)&acc[i][4];
    }
}

// ---------- K3: 9-diagonal-shift sum + argmax over l ----------
__global__ __launch_bounds__(256) void argmax_kernel(const float* __restrict__ G,
                                                     const float* __restrict__ invn,
                                                     unsigned long long* __restrict__ keys,
                                                     int lh0, int l_start, int CWP) {
    int mh = blockIdx.x;
    int lh_base = lh0 + blockIdx.y * 4;
    int wave = threadIdx.x >> 6;
    int lane = threadIdx.x & 63;
    int mwbase = wave * 16;

    float maxv[16];
    int maxi[16];
#pragma unroll
    for (int i = 0; i < 16; ++i) { maxv[i] = -INFINITY; maxi[i] = 0; }

    for (int lhs = 0; lhs < 4; ++lhs) {
        int lh = lh_base + lhs;
        int l = lh * 64 + lane;
        float inv = invn[l];
        float R[16];
#pragma unroll
        for (int i = 0; i < 16; ++i) R[i] = 0.f;

#pragma unroll
        for (int dh = -1; dh <= 1; ++dh) {
            if ((unsigned)(mh + dh) >= 64u || (unsigned)(lh + dh) >= 64u) continue;
            const float* Gb = G + (size_t)((mh + dh) * 64) * CWP + ((lh + dh) * 64 - l_start) + lane;
            float v[18];
#pragma unroll
            for (int j = 0; j < 18; ++j) {
                int mw2 = mwbase - 1 + j;
                int mwc = min(max(mw2, 0), 63);
                float tv = Gb[(size_t)mwc * CWP];
                v[j] = ((unsigned)mw2 < 64u) ? tv : 0.f;
            }
#pragma unroll
            for (int mi = 0; mi < 16; ++mi) {
                float a = __shfl_up(v[mi], 1);
                float c = __shfl_down(v[mi + 2], 1);
                float s = v[mi + 1];
                s += (lane > 0) ? a : 0.f;
                s += (lane < 63) ? c : 0.f;
                R[mi] += s;
            }
        }
#pragma unroll
        for (int mi = 0; mi < 16; ++mi) {
            float score = R[mi] * inv;
            if (score > maxv[mi]) { maxv[mi] = score; maxi[mi] = l; }
        }
    }

#pragma unroll
    for (int mi = 0; mi < 16; ++mi) {
        float v = maxv[mi];
        int idx = maxi[mi];
#pragma unroll
        for (int off = 32; off >= 1; off >>= 1) {
            float v2 = __shfl_xor(v, off);
            int i2 = __shfl_xor(idx, off);
            if (v2 > v || (v2 == v && i2 < idx)) { v = v2; idx = i2; }
        }
        if (lane == 0) {
            int m = mh * 64 + mwbase + mi;
            atomicMax(&keys[m], pack_key(v, idx));
        }
    }
}

// ---------- K4: gather matched refer patches, fold, add current, fp32 out ----------
// grid (64 rows, B, 8 channel-groups) for occupancy.
__global__ __launch_bounds__(256) void fold_kernel(const float* __restrict__ fc,
                                                   const float* __restrict__ fr,
                                                   const unsigned long long* __restrict__ keys,
                                                   float* __restrict__ out) {
    int i = blockIdx.x;
    int b = blockIdx.y;
    int cg = blockIdx.z;
    __shared__ int pos[64][9];
    for (int p = threadIdx.x; p < 576; p += 256) {
        int j = p / 9, k = p % 9;
        int kh = k / 3, kw = k % 3;
        int mhp = i + 1 - kh, mwp = j + 1 - kw;
        int ps = -1;
        if ((unsigned)mhp < 64u && (unsigned)mwp < 64u) {
            unsigned long long kk = keys[(size_t)b * HW + mhp * 64 + mwp];
            int idx = (int)(0xFFFFFFFFu - (unsigned)(kk & 0xFFFFFFFFull));
            int sh = (idx >> 6) + kh - 1;
            int sw = (idx & 63) + kw - 1;
            if ((unsigned)sh < 64u && (unsigned)sw < 64u) ps = sh * 64 + sw;
        }
        pos[j][k] = ps;
    }
    __syncthreads();
    int j = threadIdx.x & 63, cq = threadIdx.x >> 6;
    int pr[9];
#pragma unroll
    for (int k = 0; k < 9; ++k) pr[k] = pos[j][k];
    for (int c = cg * 32 + cq; c < cg * 32 + 32; c += 4) {
        const float* frow = fr + (size_t)b * CHW + (size_t)c * HW;
        float acc = fc[(size_t)b * CHW + (size_t)c * HW + i * 64 + j];
#pragma unroll
        for (int k = 0; k < 9; ++k) {
            int p = pr[k];
            float v = frow[p < 0 ? 0 : p];
            acc += (p >= 0) ? v : 0.f;
        }
        out[(size_t)b * CHW + (size_t)c * HW + i * 64 + j] = acc;
    }
}

// ---------- launch ----------
extern "C" void kernel_launch(void* const* d_in, const int* in_sizes, int n_in,
                              void* d_out, int out_size, void* d_ws, size_t ws_size,
                              hipStream_t stream) {
    const float* fc = (const float*)d_in[0];   // feature_current
    const float* fr = (const float*)d_in[1];   // feature_refer
    const float* frb = (const float*)d_in[2];  // feature_refer_blur
    float* out = (float*)d_out;

    char* ws = (char*)d_ws;
    unsigned long long* keys = (unsigned long long*)ws;  // 131072 B
    float* invn = (float*)(ws + 131072);                 //  65536 B
    float* sbuf = (float*)(ws + 196608);                 //  65536 B

    size_t abBytes = (size_t)2 * HW * 512 * sizeof(f16);  // 8,388,608
    size_t gBytes = (size_t)HW * HW * 4;                  // 67,108,864
    size_t needMfma = 262144 + abBytes + gBytes;          // ~75.8 MB

    hipMemsetAsync(keys, 0, 131072, stream);
    sqsum_kernel<<<dim3(B_, 16), 256, 0, stream>>>(frb, sbuf);
    invn_kernel<<<dim3(B_, 16), 256, 0, stream>>>(sbuf, invn);

    if (ws_size >= needMfma) {
        f16* Af = (f16*)(ws + 262144);
        f16* Bf = (f16*)(ws + 262144 + abBytes / 2);
        float* G = (float*)(ws + 262144 + abBytes);
        for (int b = 0; b < B_; ++b) {
            conv_kernel<<<dim3(64, 4, 2), 256, 0, stream>>>(
                fc + (size_t)b * CHW, frb + (size_t)b * CHW, Af, Bf);
            gram_mfma_kernel<<<dim3(32, 32), 256, 0, stream>>>(Af, Bf, G);
            argmax_kernel<<<dim3(64, 16), 256, 0, stream>>>(
                G, invn + (size_t)b * HW, keys + (size_t)b * HW, 0, 0, HW);
        }
    } else {
        // fallback: fp32 gram, chunked G
        float* G = (float*)(ws + 262144);
        int CW = 4096, PAD = 0;
        while (CW >= 256) {
            PAD = (CW == 4096) ? 0 : 128;
            size_t need = 262144 + (size_t)HW * (CW + 2 * PAD) * 4;
            if (need <= ws_size) break;
            CW >>= 1;
        }
        int CWP = CW + 2 * PAD;
        for (int b = 0; b < B_; ++b) {
            for (int cb = 0; cb < HW; cb += CW) {
                int l_start = cb - PAD;
                gram_kernel<<<dim3(CWP / 128, 32), 256, 0, stream>>>(
                    fc + (size_t)b * CHW, frb + (size_t)b * CHW, G, l_start, CWP);
                argmax_kernel<<<dim3(64, CW / 256), 256, 0, stream>>>(
                    G, invn + (size_t)b * HW, keys + (size_t)b * HW,
                    cb / 64, l_start, CWP);
            }
        }
    }
    fold_kernel<<<dim3(64, B_, 8), 256, 0, stream>>>(fc, fr, keys, out);
}

// Round 5
// 399.503 us; speedup vs baseline: 6.3812x; 1.3202x over previous
//
#include <hip/hip_runtime.h>
#include <hip/hip_bf16.h>
#include <stdint.h>

#define HW 4096
#define C_ 256
#define B_ 4

static const size_t CHW = (size_t)C_ * HW;  // 1,048,576 elements per batch per tensor

typedef _Float16 f16;
typedef f16 f16x8 __attribute__((ext_vector_type(8)));
typedef float f32x4 __attribute__((ext_vector_type(4)));

// ---------- helpers ----------
__device__ __forceinline__ unsigned long long pack_key(float v, int i) {
    // orderable float bits; tie-break: smaller l wins under max (store ~l)
    unsigned u = __float_as_uint(v);
    u = (u & 0x80000000u) ? ~u : (u | 0x80000000u);
    return ((unsigned long long)u << 32) | (unsigned long long)(0xFFFFFFFFu - (unsigned)i);
}

// ---------- K1a: per-pixel squared sum over channels of blur ----------
__global__ __launch_bounds__(256) void sqsum_kernel(const float* __restrict__ frb,
                                                    float* __restrict__ sbuf) {
    int b = blockIdx.x;
    int ij = blockIdx.y * 256 + threadIdx.x;
    const float* p = frb + (size_t)b * CHW + ij;
    float s = 0.f;
#pragma unroll 8
    for (int c = 0; c < C_; ++c) {
        float v = p[(size_t)c * HW];
        s = fmaf(v, v, s);
    }
    sbuf[b * HW + ij] = s;
}

// ---------- K1b: 3x3 box sum -> 1/max(sqrt, eps) ----------
__global__ __launch_bounds__(256) void invn_kernel(const float* __restrict__ sbuf,
                                                   float* __restrict__ invn) {
    int b = blockIdx.x;
    int l = blockIdx.y * 256 + threadIdx.x;
    int lh = l >> 6, lw = l & 63;
    float s = 0.f;
#pragma unroll
    for (int dh = -1; dh <= 1; ++dh) {
        int h = lh + dh;
        if ((unsigned)h >= 64u) continue;
#pragma unroll
        for (int dw = -1; dw <= 1; ++dw) {
            int w = lw + dw;
            if ((unsigned)w >= 64u) continue;
            s += sbuf[b * HW + h * 64 + w];
        }
    }
    float n = sqrtf(s);
    invn[b * HW + l] = 1.0f / fmaxf(n, 1e-12f);
}

// ---------- conv: fp32 [256][4096] -> f16 hi/lo, m-major [4096][512] ----------
// z=0: fc -> Af ; z=1: frb -> Bf. Tile 64k x 64m via LDS transpose.
__global__ __launch_bounds__(256) void conv_kernel(const float* __restrict__ fc,
                                                   const float* __restrict__ frb,
                                                   f16* __restrict__ Af,
                                                   f16* __restrict__ Bf) {
    const float* src = blockIdx.z ? frb : fc;
    f16* dst = blockIdx.z ? Bf : Af;
    __shared__ float T[64][65];
    int m0 = blockIdx.x * 64, k0 = blockIdx.y * 64;
    int t = threadIdx.x;
    int kl = t >> 4, mq = (t & 15) * 4;
#pragma unroll
    for (int it = 0; it < 4; ++it) {
        float4 v = *reinterpret_cast<const float4*>(src + (size_t)(k0 + kl + it * 16) * HW + m0 + mq);
        T[kl + it * 16][mq + 0] = v.x;
        T[kl + it * 16][mq + 1] = v.y;
        T[kl + it * 16][mq + 2] = v.z;
        T[kl + it * 16][mq + 3] = v.w;
    }
    __syncthreads();
    int ml = t >> 2, kc = (t & 3) * 16;
    f16x8 h0, h1, lo0, lo1;
#pragma unroll
    for (int j = 0; j < 8; ++j) {
        float a = T[kc + j][ml];
        f16 h = (f16)a;
        h0[j] = h;
        lo0[j] = (f16)(a - (float)h);
        float a2 = T[kc + 8 + j][ml];
        f16 h2 = (f16)a2;
        h1[j] = h2;
        lo1[j] = (f16)(a2 - (float)h2);
    }
    size_t base = (size_t)(m0 + ml) * 512 + k0 + kc;
    *reinterpret_cast<f16x8*>(dst + base) = h0;
    *reinterpret_cast<f16x8*>(dst + base + 8) = h1;
    *reinterpret_cast<f16x8*>(dst + base + 256) = lo0;
    *reinterpret_cast<f16x8*>(dst + base + 264) = lo1;
}

// ---------- K2 (MFMA): G[m][l] = 3-product fp16-split Gram, K=768 ----------
__global__ __launch_bounds__(256) void gram_mfma_kernel(const f16* __restrict__ Af,
                                                        const f16* __restrict__ Bf,
                                                        float* __restrict__ G) {
    __shared__ char Asb[16384];  // [128 rows][64 k] f16 = 128 B/row
    __shared__ char Bsb[16384];
    int tid = threadIdx.x;
    int lane = tid & 63;
    int wave = tid >> 6;
    int wr = wave >> 1, wc = wave & 1;
    int m0 = blockIdx.y * 128, l0 = blockIdx.x * 128;
    f32x4 acc[4][4] = {};

    char* lbaseA = Asb + (tid & ~63) * 16;  // wave-uniform; HW adds lane*16
    char* lbaseB = Bsb + (tid & ~63) * 16;

    for (int t = 0; t < 12; ++t) {
        int tt = t & 3;
        int akb = (tt * 64 + ((t >= 4 && t < 8) ? 256 : 0)) * 2;  // bytes into row
        int bkb = (tt * 64 + ((t >= 8) ? 256 : 0)) * 2;
#pragma unroll
        for (int i = 0; i < 4; ++i) {
            int c = i * 256 + tid;
            int m = c >> 3, cl = c & 7;
            int sw = ((cl ^ (m & 7)) << 4);
            const char* ga = (const char*)Af + (size_t)(m0 + m) * 1024 + akb + sw;
            const char* gb = (const char*)Bf + (size_t)(l0 + m) * 1024 + bkb + sw;
            __builtin_amdgcn_global_load_lds(
                (const __attribute__((address_space(1))) uint32_t*)ga,
                (__attribute__((address_space(3))) uint32_t*)(lbaseA + i * 4096), 16, 0, 0);
            __builtin_amdgcn_global_load_lds(
                (const __attribute__((address_space(1))) uint32_t*)gb,
                (__attribute__((address_space(3))) uint32_t*)(lbaseB + i * 4096), 16, 0, 0);
        }
        __syncthreads();
#pragma unroll
        for (int kk = 0; kk < 2; ++kk) {
            f16x8 av[4], bv[4];
#pragma unroll
            for (int q = 0; q < 4; ++q) {
                int mrow = wr * 64 + q * 16 + (lane & 15);
                int nrow = wc * 64 + q * 16 + (lane & 15);
                int ch = ((kk * 4 + (lane >> 4)) ^ (lane & 7)) << 4;
                av[q] = *reinterpret_cast<const f16x8*>(Asb + mrow * 128 + ch);
                bv[q] = *reinterpret_cast<const f16x8*>(Bsb + nrow * 128 + ch);
            }
#pragma unroll
            for (int mi = 0; mi < 4; ++mi)
#pragma unroll
                for (int ni = 0; ni < 4; ++ni)
                    acc[mi][ni] = __builtin_amdgcn_mfma_f32_16x16x32_f16(
                        av[mi], bv[ni], acc[mi][ni], 0, 0, 0);
        }
        __syncthreads();
    }
#pragma unroll
    for (int mi = 0; mi < 4; ++mi) {
#pragma unroll
        for (int ni = 0; ni < 4; ++ni) {
            int n = l0 + wc * 64 + ni * 16 + (lane & 15);
            int mr = m0 + wr * 64 + mi * 16 + (lane >> 4) * 4;
#pragma unroll
            for (int r = 0; r < 4; ++r)
                G[(size_t)(mr + r) * HW + n] = acc[mi][ni][r];
        }
    }
}

// ---------- K2 fallback: fp32 Gram GEMM (chunked) ----------
#define TBK 32
__global__ __launch_bounds__(256) void gram_kernel(const float* __restrict__ Amat,
                                                   const float* __restrict__ Bmat,
                                                   float* __restrict__ G,
                                                   int l_start, int CWP) {
    __shared__ float As[TBK][128];
    __shared__ float Bs[TBK][128];
    int m0 = blockIdx.y * 128;
    int l0g = l_start + blockIdx.x * 128;
    bool inrange = (l0g >= 0 && l0g < HW);
    int tid = threadIdx.x;
    int tx = tid & 15;
    int ty = tid >> 4;
    float acc[8][8] = {};

    if (inrange) {
        for (int k0 = 0; k0 < C_; k0 += TBK) {
#pragma unroll
            for (int it = 0; it < 4; ++it) {
                int idx = tid + it * 256;
                int r = idx >> 5;
                int c4 = idx & 31;
                float4 av = *reinterpret_cast<const float4*>(Amat + (size_t)(k0 + r) * HW + m0 + c4 * 4);
                *reinterpret_cast<float4*>(&As[r][c4 * 4]) = av;
                float4 bv = *reinterpret_cast<const float4*>(Bmat + (size_t)(k0 + r) * HW + l0g + c4 * 4);
                *reinterpret_cast<float4*>(&Bs[r][c4 * 4]) = bv;
            }
            __syncthreads();
#pragma unroll
            for (int k = 0; k < TBK; ++k) {
                float a[8], bb[8];
                *(float4*)&a[0] = *(float4*)&As[k][ty * 8];
                *(float4*)&a[4] = *(float4*)&As[k][ty * 8 + 4];
                *(float4*)&bb[0] = *(float4*)&Bs[k][tx * 8];
                *(float4*)&bb[4] = *(float4*)&Bs[k][tx * 8 + 4];
#pragma unroll
                for (int i = 0; i < 8; ++i)
#pragma unroll
                    for (int j = 0; j < 8; ++j)
                        acc[i][j] = fmaf(a[i], bb[j], acc[i][j]);
            }
            __syncthreads();
        }
    }
#pragma unroll
    for (int i = 0; i < 8; ++i) {
        int m = m0 + ty * 8 + i;
        float* row = G + (size_t)m * CWP + blockIdx.x * 128 + tx * 8;
        *(float4*)row = *(float4*)&acc[i][0];
        *(float4*)(row + 4) = *(float4*)&acc[i][4];
    }
}

// ---------- K3: 9-diagonal-shift sum + argmax over l ----------
__global__ __launch_bounds__(256) void argmax_kernel(const float* __restrict__ G,
                                                     const float* __restrict__ invn,
                                                     unsigned long long* __restrict__ keys,
                                                     int lh0, int l_start, int CWP) {
    int mh = blockIdx.x;
    int lh_base = lh0 + blockIdx.y * 4;
    int wave = threadIdx.x >> 6;
    int lane = threadIdx.x & 63;
    int mwbase = wave * 16;

    float maxv[16];
    int maxi[16];
#pragma unroll
    for (int i = 0; i < 16; ++i) { maxv[i] = -INFINITY; maxi[i] = 0; }

    for (int lhs = 0; lhs < 4; ++lhs) {
        int lh = lh_base + lhs;
        int l = lh * 64 + lane;
        float inv = invn[l];
        float R[16];
#pragma unroll
        for (int i = 0; i < 16; ++i) R[i] = 0.f;

#pragma unroll
        for (int dh = -1; dh <= 1; ++dh) {
            if ((unsigned)(mh + dh) >= 64u || (unsigned)(lh + dh) >= 64u) continue;
            const float* Gb = G + (size_t)((mh + dh) * 64) * CWP + ((lh + dh) * 64 - l_start) + lane;
            float v[18];
#pragma unroll
            for (int j = 0; j < 18; ++j) {
                int mw2 = mwbase - 1 + j;
                int mwc = min(max(mw2, 0), 63);
                float tv = Gb[(size_t)mwc * CWP];
                v[j] = ((unsigned)mw2 < 64u) ? tv : 0.f;
            }
#pragma unroll
            for (int mi = 0; mi < 16; ++mi) {
                float a = __shfl_up(v[mi], 1);
                float c = __shfl_down(v[mi + 2], 1);
                float s = v[mi + 1];
                s += (lane > 0) ? a : 0.f;
                s += (lane < 63) ? c : 0.f;
                R[mi] += s;
            }
        }
#pragma unroll
        for (int mi = 0; mi < 16; ++mi) {
            float score = R[mi] * inv;
            if (score > maxv[mi]) { maxv[mi] = score; maxi[mi] = l; }
        }
    }

#pragma unroll
    for (int mi = 0; mi < 16; ++mi) {
        float v = maxv[mi];
        int idx = maxi[mi];
#pragma unroll
        for (int off = 32; off >= 1; off >>= 1) {
            float v2 = __shfl_xor(v, off);
            int i2 = __shfl_xor(idx, off);
            if (v2 > v || (v2 == v && i2 < idx)) { v = v2; idx = i2; }
        }
        if (lane == 0) {
            int m = mh * 64 + mwbase + mi;
            atomicMax(&keys[m], pack_key(v, idx));
        }
    }
}

// ---------- K4: LDS-staged gather-fold. Block = (2 channels, batch). ----------
// Stage fr[c0..c0+1] (32 KB) + decoded idx (16 KB) in LDS; all gathers hit LDS.
// 4 waves: (channel, i-half); lanes = j. Streams fc/out coalesced.
__global__ __launch_bounds__(256) void fold_kernel(const float* __restrict__ fc,
                                                   const float* __restrict__ fr,
                                                   const unsigned long long* __restrict__ keys,
                                                   float* __restrict__ out) {
    int b = blockIdx.y;
    int c0 = blockIdx.x * 2;
    __shared__ float frL[2 * 4096];
    __shared__ int idxL[4096];
    int t = threadIdx.x;

    const float* fsrc = fr + (size_t)b * CHW + (size_t)c0 * HW;
#pragma unroll
    for (int it = 0; it < 8; ++it) {
        int o = (it * 256 + t) * 4;
        *reinterpret_cast<float4*>(&frL[o]) = *reinterpret_cast<const float4*>(&fsrc[o]);
    }
#pragma unroll
    for (int it = 0; it < 16; ++it) {
        int m = it * 256 + t;
        unsigned long long kk = keys[(size_t)b * HW + m];
        idxL[m] = (int)(0xFFFFFFFFu - (unsigned)(kk & 0xFFFFFFFFull));
    }
    __syncthreads();

    int j = t & 63, w = t >> 6;
    int c = c0 + (w & 1);
    int i0 = (w >> 1) * 32;
    const float* frowL = &frL[(w & 1) * 4096];
    const float* fcrow = fc + (size_t)b * CHW + (size_t)c * HW;
    float* orow = out + (size_t)b * CHW + (size_t)c * HW;

    for (int i = i0; i < i0 + 32; ++i) {
        float acc = fcrow[i * 64 + j];
#pragma unroll
        for (int kh = 0; kh < 3; ++kh) {
            int mhp = i + 1 - kh;
            if ((unsigned)mhp >= 64u) continue;
#pragma unroll
            for (int kw = 0; kw < 3; ++kw) {
                int mwp = j + 1 - kw;
                float contrib = 0.f;
                if ((unsigned)mwp < 64u) {
                    int idx = idxL[mhp * 64 + mwp];
                    int sh = (idx >> 6) + kh - 1;
                    int sw = (idx & 63) + kw - 1;
                    if ((unsigned)sh < 64u && (unsigned)sw < 64u)
                        contrib = frowL[sh * 64 + sw];
                }
                acc += contrib;
            }
        }
        orow[i * 64 + j] = acc;
    }
}

// ---------- launch ----------
extern "C" void kernel_launch(void* const* d_in, const int* in_sizes, int n_in,
                              void* d_out, int out_size, void* d_ws, size_t ws_size,
                              hipStream_t stream) {
    const float* fc = (const float*)d_in[0];   // feature_current
    const float* fr = (const float*)d_in[1];   // feature_refer
    const float* frb = (const float*)d_in[2];  // feature_refer_blur
    float* out = (float*)d_out;

    char* ws = (char*)d_ws;
    unsigned long long* keys = (unsigned long long*)ws;  // 131072 B
    float* invn = (float*)(ws + 131072);                 //  65536 B
    float* sbuf = (float*)(ws + 196608);                 //  65536 B

    size_t abBytes = (size_t)2 * HW * 512 * sizeof(f16);  // 8,388,608
    size_t gBytes = (size_t)HW * HW * 4;                  // 67,108,864
    size_t needMfma = 262144 + abBytes + gBytes;          // ~75.8 MB

    hipMemsetAsync(keys, 0, 131072, stream);
    sqsum_kernel<<<dim3(B_, 16), 256, 0, stream>>>(frb, sbuf);
    invn_kernel<<<dim3(B_, 16), 256, 0, stream>>>(sbuf, invn);

    if (ws_size >= needMfma) {
        f16* Af = (f16*)(ws + 262144);
        f16* Bf = (f16*)(ws + 262144 + abBytes / 2);
        float* G = (float*)(ws + 262144 + abBytes);
        for (int b = 0; b < B_; ++b) {
            conv_kernel<<<dim3(64, 4, 2), 256, 0, stream>>>(
                fc + (size_t)b * CHW, frb + (size_t)b * CHW, Af, Bf);
            gram_mfma_kernel<<<dim3(32, 32), 256, 0, stream>>>(Af, Bf, G);
            argmax_kernel<<<dim3(64, 16), 256, 0, stream>>>(
                G, invn + (size_t)b * HW, keys + (size_t)b * HW, 0, 0, HW);
        }
    } else {
        float* G = (float*)(ws + 262144);
        int CW = 4096, PAD = 0;
        while (CW >= 256) {
            PAD = (CW == 4096) ? 0 : 128;
            size_t need = 262144 + (size_t)HW * (CW + 2 * PAD) * 4;
            if (need <= ws_size) break;
            CW >>= 1;
        }
        int CWP = CW + 2 * PAD;
        for (int b = 0; b < B_; ++b) {
            for (int cb = 0; cb < HW; cb += CW) {
                int l_start = cb - PAD;
                gram_kernel<<<dim3(CWP / 128, 32), 256, 0, stream>>>(
                    fc + (size_t)b * CHW, frb + (size_t)b * CHW, G, l_start, CWP);
                argmax_kernel<<<dim3(64, CW / 256), 256, 0, stream>>>(
                    G, invn + (size_t)b * HW, keys + (size_t)b * HW,
                    cb / 64, l_start, CWP);
            }
        }
    }
    fold_kernel<<<dim3(128, B_), 256, 0, stream>>>(fc, fr, keys, out);
}